// Round 12
// baseline (2391.248 us; speedup 1.0000x reference)
//
#include <hip/hip_runtime.h>
#include <math.h>

#define B_  4
#define L_  512
#define D_  512
#define DIN 1024
#define DST 16
#define DCV 4
#define DTR 32
#define NL  3
#define H2  256

typedef _Float16 __f16;
typedef __f16 f16x2 __attribute__((ext_vector_type(2)));
typedef __f16 half8 __attribute__((ext_vector_type(8)));
typedef float f32x4v __attribute__((ext_vector_type(4)));
typedef unsigned uint4v __attribute__((ext_vector_type(4)));

__device__ __forceinline__ float fast_sigmoid(float x) { return 1.f / (1.f + __expf(-x)); }
__device__ __forceinline__ float fast_tanh(float x) { return 2.f / (1.f + __expf(-2.f * x)) - 1.f; }

__device__ __forceinline__ float dot2f(unsigned a, unsigned b, float c) {
  return __builtin_amdgcn_fdot2(__builtin_bit_cast(f16x2, a),
                                __builtin_bit_cast(f16x2, b), c, false);
}
__device__ __forceinline__ unsigned packf16(float a, float b) {
  f16x2 p; p.x = (__f16)a; p.y = (__f16)b;
  return __builtin_bit_cast(unsigned, p);
}

// ---------------- f16 MFMA GEMM: C[M,N] = A[M,K] @ W[N,K]^T (+bias +bias2) ----------------
template<bool ACC>
__global__ __launch_bounds__(256) void gemm_mfma(
    const float* __restrict__ A, const float* __restrict__ W, float* __restrict__ C,
    int M, int N, int K, int lda, int ldb, int ldc,
    const float* __restrict__ bias, const float* __restrict__ bias2)
{
  __shared__ uint4v As[1024];   // [row][8 kb-slots], phys slot = kb ^ (row&7), 16KB
  __shared__ uint4v Bs[1024];   // 16KB
  const int tid  = threadIdx.x;
  const int lane = tid & 63, wid = tid >> 6;
  const int wr = wid >> 1, wc = wid & 1;
  const int fr = lane & 15, fq = lane >> 4;
  const int m0 = blockIdx.y * 128, n0 = blockIdx.x * 128;
  const int srow = tid >> 3, skb = tid & 7;

  f32x4v acc[4][4] = {};
  for (int k0 = 0; k0 < K; k0 += 64) {
    const float* Abase = A + (size_t)m0 * lda + k0;
    const float* Bbase = W + (size_t)n0 * ldb + k0;
    #pragma unroll
    for (int i = 0; i < 4; ++i) {
      int row = srow + i * 32;
      const float4* pa = (const float4*)(Abase + (size_t)row * lda + skb * 8);
      const float4* pb = (const float4*)(Bbase + (size_t)row * ldb + skb * 8);
      float4 a0 = pa[0], a1 = pa[1];
      float4 b0 = pb[0], b1 = pb[1];
      uint4v ap, bp;
      ap.x = packf16(a0.x, a0.y); ap.y = packf16(a0.z, a0.w);
      ap.z = packf16(a1.x, a1.y); ap.w = packf16(a1.z, a1.w);
      bp.x = packf16(b0.x, b0.y); bp.y = packf16(b0.z, b0.w);
      bp.z = packf16(b1.x, b1.y); bp.w = packf16(b1.z, b1.w);
      As[row * 8 + (skb ^ (row & 7))] = ap;
      Bs[row * 8 + (skb ^ (row & 7))] = bp;
    }
    __syncthreads();
    #pragma unroll
    for (int ks = 0; ks < 2; ++ks) {
      half8 af[4], bf[4];
      #pragma unroll
      for (int mt = 0; mt < 4; ++mt) {
        int row = wr * 64 + mt * 16 + fr;
        int kb = ks * 4 + fq;
        af[mt] = __builtin_bit_cast(half8, As[row * 8 + (kb ^ (row & 7))]);
      }
      #pragma unroll
      for (int nt = 0; nt < 4; ++nt) {
        int row = wc * 64 + nt * 16 + fr;
        int kb = ks * 4 + fq;
        bf[nt] = __builtin_bit_cast(half8, Bs[row * 8 + (kb ^ (row & 7))]);
      }
      #pragma unroll
      for (int mt = 0; mt < 4; ++mt)
        #pragma unroll
        for (int nt = 0; nt < 4; ++nt)
          acc[mt][nt] = __builtin_amdgcn_mfma_f32_16x16x32_f16(af[mt], bf[nt], acc[mt][nt], 0, 0, 0);
    }
    __syncthreads();
  }
  #pragma unroll
  for (int nt = 0; nt < 4; ++nt) {
    int n = n0 + wc * 64 + nt * 16 + fr;
    float bv = (bias ? bias[n] : 0.f) + (bias2 ? bias2[n] : 0.f);
    #pragma unroll
    for (int mt = 0; mt < 4; ++mt) {
      #pragma unroll
      for (int r = 0; r < 4; ++r) {
        int m = m0 + wr * 64 + mt * 16 + fq * 4 + r;
        float v = acc[mt][nt][r] + bv;
        if (ACC) C[(size_t)m * ldc + n] += v; else C[(size_t)m * ldc + n] = v;
      }
    }
  }
}

// ---------------- fp32 fallback GEMM (small/odd shapes) ----------------
template<int ACT>
__global__ __launch_bounds__(256) void gemm_nt(
    const float* __restrict__ A, const float* __restrict__ Bm, float* __restrict__ C,
    int M, int N, int K, int lda, int ldb, int ldc,
    const float* __restrict__ bias)
{
  __shared__ __align__(16) float As[16][64];
  __shared__ __align__(16) float Bs[16][64];
  const int tid = threadIdx.x;
  const int tx = tid & 15, ty = tid >> 4;
  const int m0 = blockIdx.y * 64, n0 = blockIdx.x * 64;
  const int r = tid >> 2, kq = (tid & 3) * 4;
  float acc[4][4] = {};
  for (int k0 = 0; k0 < K; k0 += 16) {
    float4 av = *(const float4*)(A  + (size_t)(m0 + r) * lda + (k0 + kq));
    float4 bv = *(const float4*)(Bm + (size_t)(n0 + r) * ldb + (k0 + kq));
    As[kq+0][r] = av.x; As[kq+1][r] = av.y; As[kq+2][r] = av.z; As[kq+3][r] = av.w;
    Bs[kq+0][r] = bv.x; Bs[kq+1][r] = bv.y; Bs[kq+2][r] = bv.z; Bs[kq+3][r] = bv.w;
    __syncthreads();
    #pragma unroll
    for (int kk = 0; kk < 16; ++kk) {
      float4 a = *(const float4*)(&As[kk][ty*4]);
      float4 b = *(const float4*)(&Bs[kk][tx*4]);
      float aa[4] = {a.x, a.y, a.z, a.w};
      float bb[4] = {b.x, b.y, b.z, b.w};
      #pragma unroll
      for (int i = 0; i < 4; ++i)
        #pragma unroll
        for (int j = 0; j < 4; ++j)
          acc[i][j] = fmaf(aa[i], bb[j], acc[i][j]);
    }
    __syncthreads();
  }
  #pragma unroll
  for (int i = 0; i < 4; ++i) {
    int m = m0 + ty*4 + i;
    float* cp = C + (size_t)m * ldc + n0 + tx*4;
    #pragma unroll
    for (int j = 0; j < 4; ++j) {
      int n = n0 + tx*4 + j;
      float v = acc[i][j];
      if (bias)  v += bias[n];
      if (ACT == 1) v = (v > 20.f) ? v : log1pf(__expf(v));
      cp[j] = v;
    }
  }
}

// xpw_pad[r][k] = r<64 ? xpw[r][k] : 0   (128x1024)
__global__ __launch_bounds__(256) void pad_xpw(
    const float* __restrict__ src, float* __restrict__ dst)
{
  int t = blockIdx.x * 256 + threadIdx.x;
  int r = t >> 10;
  dst[t] = (r < 64) ? src[t] : 0.f;
}

// pack whh f32 -> f16 uint4, layout [dir][gate G][q][t] with t=(j<<1)|ks:
// wpk[((dir*4+G)*16+q)*512 + t] covers whh[dir][(G*256+j)][ks*128 + q*8 .. +8)
__global__ __launch_bounds__(256) void pack_whh(
    const float* __restrict__ whh, uint4* __restrict__ wpk)
{
  int idx = blockIdx.x * 256 + threadIdx.x;   // [0, 65536)
  int t = idx & 511;
  int q = (idx >> 9) & 15;
  int G = (idx >> 13) & 3;
  int dir = idx >> 15;
  int j = t >> 1, ks = t & 1;
  const float* src = whh + (size_t)dir * 262144 + (size_t)(G * 256 + j) * 256 + ks * 128 + q * 8;
  float4 fa = ((const float4*)src)[0];
  float4 fb = ((const float4*)src)[1];
  uint4 pk;
  pk.x = packf16(fa.x, fa.y); pk.y = packf16(fa.z, fa.w);
  pk.z = packf16(fb.x, fb.y); pk.w = packf16(fb.z, fb.w);
  wpk[idx] = pk;
}

// u[b,l,c] = silu(cb[c] + sum_k xin[b,l-3+k,c] * cw[c,k])
__global__ __launch_bounds__(256) void conv_silu(
    const float* __restrict__ xz, const float* __restrict__ cw, const float* __restrict__ cb,
    float* __restrict__ u)
{
  int t = blockIdx.x * 256 + threadIdx.x;
  int c  = t & (DIN - 1);
  int bl = t >> 10;
  int l  = bl & (L_ - 1);
  float acc = cb[c];
  #pragma unroll
  for (int k = 0; k < DCV; ++k) {
    int ls = l + k - (DCV - 1);
    if (ls >= 0)
      acc = fmaf(xz[(size_t)(bl + k - (DCV - 1)) * 2048 + c], cw[c * DCV + k], acc);
  }
  u[t] = acc * fast_sigmoid(acc);
}

// selective scan: thread per (b,c,n); next-step inputs software-prefetched.
__global__ __launch_bounds__(256) void scan_kernel(
    const float* __restrict__ dt, const float* __restrict__ u,
    const float* __restrict__ xdbl, const float* __restrict__ xz,
    const float* __restrict__ A_log, const float* __restrict__ Dp,
    float* __restrict__ y)
{
  int t = blockIdx.x * 256 + threadIdx.x;
  int n  = t & 15;
  int bc = t >> 4;
  int c  = bc & (DIN - 1);
  int b  = bc >> 10;
  float Ac = -__expf(A_log[c * DST + n]);
  float Dc = Dp[c];
  float h = 0.f;
  const size_t row = (size_t)b * L_;
  float dtv = dt[row * DIN + c];
  float uv  = u [row * DIN + c];
  float Bn  = xdbl[row * 128 + 32 + n];
  float Cn  = xdbl[row * 128 + 48 + n];
  float zv  = xz[row * 2048 + 1024 + c];
  for (int l = 0; l < L_; ++l) {
    float dt_n = 0.f, u_n = 0.f, B_n = 0.f, C_n = 0.f, z_n = 0.f;
    if (l + 1 < L_) {
      const size_t nb = row + l + 1;
      dt_n = dt[nb * DIN + c];
      u_n  = u [nb * DIN + c];
      B_n  = xdbl[nb * 128 + 32 + n];
      C_n  = xdbl[nb * 128 + 48 + n];
      z_n  = xz[nb * 2048 + 1024 + c];
    }
    float dA = __expf(dtv * Ac);
    h = fmaf(dA, h, (dtv * uv) * Bn);
    float p = h * Cn;
    p += __shfl_xor(p, 1, 64);
    p += __shfl_xor(p, 2, 64);
    p += __shfl_xor(p, 4, 64);
    p += __shfl_xor(p, 8, 64);
    if (n == 0) {
      float yv = p + uv * Dc;
      yv *= zv * fast_sigmoid(zv);
      y[(row + l) * DIN + c] = yv;
    }
    dtv = dt_n; uv = u_n; Bn = B_n; Cn = C_n; zv = z_n;
  }
}

// out[row*ldo + col0 + c] = layernorm(a[row] + mo[row]) * g + b
__global__ __launch_bounds__(64) void resid_ln(
    const float* __restrict__ a, const float* __restrict__ mo,
    const float* __restrict__ g, const float* __restrict__ bta,
    float* __restrict__ outm, int ldo)
{
  int row = blockIdx.x;
  int lane = threadIdx.x;
  const float* pa = a  + (size_t)row * 512;
  const float* pb = mo + (size_t)row * 512;
  float v[8];
  float s = 0.f, s2 = 0.f;
  #pragma unroll
  for (int i = 0; i < 8; ++i) {
    float x = pa[lane + i * 64] + pb[lane + i * 64];
    v[i] = x; s += x; s2 += x * x;
  }
  #pragma unroll
  for (int off = 1; off < 64; off <<= 1) {
    s  += __shfl_xor(s,  off, 64);
    s2 += __shfl_xor(s2, off, 64);
  }
  float mean = s * (1.f / 512.f);
  float var  = s2 * (1.f / 512.f) - mean * mean;
  float rstd = rsqrtf(var + 1e-5f);
  #pragma unroll
  for (int i = 0; i < 8; ++i) {
    int cidx = lane + i * 64;
    outm[(size_t)row * ldo + cidx] = (v[i] - mean) * rstd * g[cidx] + bta[cidx];
  }
}

// ---------------- LSTM recurrence ----------------
// Block per (dir,b), 512 threads = (unit j = t>>1) x (K-half ks = t&1).
// i-gate: 16 named uint4 (64 VGPRs) loaded pre-loop -- small enough to fit
// under the 128-VGPR cap (r5-r11: larger sets always remat from L2).
// f,g gates: EXPLICIT in-loop loads through asm-laundered pointers (cannot be
// hoisted -> issue fresh each step, pipelined under the dot2 chain; 256 KB/step
// L2 stream vs r9's 384). Gate o streamed from LDS [q][t] (wave-contiguous).
// h packed-f16 in LDS, double-buffered; gx prefetched. One barrier per step.

#define WIDECL(q) uint4 WI##q;
#define WILOAD(q) WI##q = wp[(0 * 16 + (q)) * 512 + t];
#define WSTEP(q) { \
    uint4 hv = h4s[buf][(q) * 2 + ks]; \
    uint4 wv = wo_lds[(q) * 512 + t]; \
    uint4 fv = wfp[(q) * 512]; \
    uint4 gv = wgp[(q) * 512]; \
    a0 = dot2f(WI##q.x, hv.x, a0); a0 = dot2f(WI##q.y, hv.y, a0); \
    a0 = dot2f(WI##q.z, hv.z, a0); a0 = dot2f(WI##q.w, hv.w, a0); \
    a1 = dot2f(fv.x, hv.x, a1); a1 = dot2f(fv.y, hv.y, a1); \
    a1 = dot2f(fv.z, hv.z, a1); a1 = dot2f(fv.w, hv.w, a1); \
    a2 = dot2f(gv.x, hv.x, a2); a2 = dot2f(gv.y, hv.y, a2); \
    a2 = dot2f(gv.z, hv.z, a2); a2 = dot2f(gv.w, hv.w, a2); \
    a3 = dot2f(wv.x, hv.x, a3); a3 = dot2f(wv.y, hv.y, a3); \
    a3 = dot2f(wv.z, hv.z, a3); a3 = dot2f(wv.w, hv.w, a3); \
  }
#define REP16(M) M(0) M(1) M(2) M(3) M(4) M(5) M(6) M(7) \
                 M(8) M(9) M(10) M(11) M(12) M(13) M(14) M(15)

__global__ __launch_bounds__(512, 1) void lstm_rec(
    const float* __restrict__ gx, const uint4* __restrict__ wpk,
    float* __restrict__ comb)
{
  __shared__ uint4 wo_lds[16 * 512];            // [q][t], 128KB o-gate weights
  __shared__ __align__(16) uint4 h4s[2][32];    // [buf][q*2+ks], packed-f16 h
  const int dir = blockIdx.x >> 2, b = blockIdx.x & 3;
  const int t = threadIdx.x;
  const int j = t >> 1, ks = t & 1;
  const uint4* wp = wpk + (size_t)dir * 4 * 16 * 512;

  REP16(WIDECL)
  REP16(WILOAD)

  #pragma unroll
  for (int q = 0; q < 16; ++q)
    wo_lds[q * 512 + t] = wp[(3 * 16 + q) * 512 + t];

  if (t < 256) ((unsigned*)h4s)[t] = 0u;
  float c_reg = 0.f;
  float* outp = comb + 512 + dir * 256;        // columns [512+dir*256, +256) of comb
  const float* gxb = gx + (size_t)(b * L_) * 2048 + dir * 1024;
  const int offA = (ks ? 1 : 0) * 256 + j;   // ks0 -> gate i, ks1 -> gate f
  const int offB = (ks ? 3 : 2) * 256 + j;   // ks0 -> gate g, ks1 -> gate o
  const int p_   = t >> 2;
  const int hidx = ((p_ >> 2) & 15) * 8 + (p_ >> 6) * 4 + (p_ & 3);
  __syncthreads();

  int buf = 0;
  const int l0 = dir ? (L_ - 1) : 0;
  float pgA = gxb[(size_t)l0 * 2048 + offA];
  float pgB = gxb[(size_t)l0 * 2048 + offB];

  for (int s = 0; s < L_; ++s) {
    const int l = dir ? (L_ - 1 - s) : s;
    float pgA_n = 0.f, pgB_n = 0.f;
    if (s + 1 < L_) {
      const int ln = dir ? (L_ - 2 - s) : (s + 1);
      pgA_n = gxb[(size_t)ln * 2048 + offA];
      pgB_n = gxb[(size_t)ln * 2048 + offB];
    }
    // laundered f/g base pointers: opaque to LICM -> loads issue this iteration
    const uint4* wfp = wp + (1 * 16) * 512 + t;
    const uint4* wgp = wp + (2 * 16) * 512 + t;
    {
      unsigned long long f_ = (unsigned long long)wfp;
      unsigned long long g_ = (unsigned long long)wgp;
      asm volatile("" : "+v"(f_), "+v"(g_));
      wfp = (const uint4*)f_;
      wgp = (const uint4*)g_;
    }
    float a0 = 0.f, a1 = 0.f, a2 = 0.f, a3 = 0.f;
    REP16(WSTEP)
    if (ks == 0) { a0 += pgA; a2 += pgB; } else { a1 += pgA; a3 += pgB; }
    a0 += __shfl_xor(a0, 1, 64);
    a1 += __shfl_xor(a1, 1, 64);
    a2 += __shfl_xor(a2, 1, 64);
    a3 += __shfl_xor(a3, 1, 64);
    const float si = fast_sigmoid(a0);
    const float sf = fast_sigmoid(a1);
    const float tg = fast_tanh(a2);
    const float so = fast_sigmoid(a3);
    c_reg = fmaf(sf, c_reg, si * tg);
    const float hv = so * fast_tanh(c_reg);
    if (ks == 0) outp[(size_t)(b * L_ + l) * 1024 + j] = hv;
    const float hv2 = __shfl_xor(hv, 2, 64);   // h of unit j+1 (for even j, ks=0)
    if ((t & 3) == 0)
      ((unsigned*)h4s[buf ^ 1])[hidx] = packf16(hv, hv2);
    pgA = pgA_n; pgB = pgB_n;
    buf ^= 1;
    __syncthreads();
  }
}

extern "C" void kernel_launch(void* const* d_in, const int* in_sizes, int n_in,
                              void* d_out, int out_size, void* d_ws, size_t ws_size,
                              hipStream_t stream)
{
  const float* x    = (const float*)d_in[0];
  const float* wi   = (const float*)d_in[1];
  const float* cw   = (const float*)d_in[2];
  const float* cb   = (const float*)d_in[3];
  const float* xpw  = (const float*)d_in[4];
  const float* dw   = (const float*)d_in[5];
  const float* db   = (const float*)d_in[6];
  const float* Alog = (const float*)d_in[7];
  const float* Dp   = (const float*)d_in[8];
  const float* wo   = (const float*)d_in[9];
  const float* lng  = (const float*)d_in[10];
  const float* lnb  = (const float*)d_in[11];
  const float* wih  = (const float*)d_in[12];
  const float* whh  = (const float*)d_in[13];
  const float* bih  = (const float*)d_in[14];
  const float* bhh  = (const float*)d_in[15];
  const float* fw   = (const float*)d_in[16];
  const float* fb   = (const float*)d_in[17];
  float* out = (float*)d_out;

  float* F    = (float*)d_ws;
  float* xz   = F;                 // 4,194,304 floats; aliased with gx
  float* gx   = F;
  float* u    = F + 4194304;       // 2,097,152
  float* xdbl = F + 6291456;       //   262,144 (2048 x 128, padded)
  float* dt   = F + 6553600;       // 2,097,152
  float* ybuf = F + 8650752;       // 2,097,152
  float* mo   = F + 10747904;      // 1,048,576
  float* mbuf = F + 11796480;      // 1,048,576
  float* comb = F + 12845056;      // 2,097,152  [m | lf | lb], ld 1024
  uint4* wpk  = (uint4*)(F + 14942208);  // 1MB packed whh
  float* xpw_pad = mo;             // pad consumed before mo is written

  const int M = B_ * L_;           // 2048
  dim3 blk(256);

  gemm_mfma<false><<<dim3(2048/128, M/128), blk, 0, stream>>>(
      x, wih, gx, M, 2048, 512, 512, 512, 2048, bih, bhh);
  pack_whh<<<dim3(256), blk, 0, stream>>>(whh, wpk);
  lstm_rec<<<dim3(8), dim3(512), 0, stream>>>(gx, wpk, comb);

  for (int i = 0; i < NL; ++i) {
    const float* min = (i == 0) ? x : mbuf;
    pad_xpw<<<dim3(512), blk, 0, stream>>>(xpw + (size_t)i*64*1024, xpw_pad);
    gemm_mfma<false><<<dim3(2048/128, M/128), blk, 0, stream>>>(
        min, wi + (size_t)i*2048*512, xz, M, 2048, 512, 512, 512, 2048, nullptr, nullptr);
    conv_silu<<<dim3((M*DIN)/256), blk, 0, stream>>>(
        xz, cw + (size_t)i*DIN*DCV, cb + i*DIN, u);
    gemm_mfma<false><<<dim3(1, M/128), blk, 0, stream>>>(
        u, xpw_pad, xdbl, M, 128, 1024, 1024, 1024, 128, nullptr, nullptr);
    gemm_nt<1><<<dim3(1024/64, M/64), blk, 0, stream>>>(
        xdbl, dw + (size_t)i*1024*32, dt, M, 1024, 32, 128, 32, 1024, db + i*1024);
    scan_kernel<<<dim3((B_*DIN*DST)/256), blk, 0, stream>>>(
        dt, u, xdbl, xz, Alog + (size_t)i*DIN*DST, Dp + i*DIN, ybuf);
    gemm_mfma<false><<<dim3(512/128, M/128), blk, 0, stream>>>(
        ybuf, wo + (size_t)i*512*1024, mo, M, 512, 1024, 1024, 1024, 512, nullptr, nullptr);
    // m = layernorm(m + mo); last layer writes directly into comb cols [0,512)
    if (i < NL - 1)
      resid_ln<<<dim3(M), dim3(64), 0, stream>>>(
          min, mo, lng + i*512, lnb + i*512, mbuf, 512);
    else
      resid_ln<<<dim3(M), dim3(64), 0, stream>>>(
          min, mo, lng + i*512, lnb + i*512, comb, 1024);
  }

  // fusion: out = comb @ fusion_w^T + fb  (single K=1024 MFMA GEMM)
  gemm_mfma<false><<<dim3(512/128, M/128), blk, 0, stream>>>(
      comb, fw, out, M, 512, 1024, 1024, 1024, 512, fb, nullptr);
}

// Round 13
// 1575.018 us; speedup vs baseline: 1.5182x; 1.5182x over previous
//
#include <hip/hip_runtime.h>
#include <math.h>

#define B_  4
#define L_  512
#define D_  512
#define DIN 1024
#define DST 16
#define DCV 4
#define DTR 32
#define NL  3
#define H2  256

typedef _Float16 __f16;
typedef __f16 f16x2 __attribute__((ext_vector_type(2)));
typedef __f16 half8 __attribute__((ext_vector_type(8)));
typedef float f32x4v __attribute__((ext_vector_type(4)));
typedef unsigned uint4v __attribute__((ext_vector_type(4)));

__device__ __forceinline__ float fast_sigmoid(float x) { return 1.f / (1.f + __expf(-x)); }
__device__ __forceinline__ float fast_tanh(float x) { return 2.f / (1.f + __expf(-2.f * x)) - 1.f; }

__device__ __forceinline__ float dot2f(unsigned a, unsigned b, float c) {
  return __builtin_amdgcn_fdot2(__builtin_bit_cast(f16x2, a),
                                __builtin_bit_cast(f16x2, b), c, false);
}
__device__ __forceinline__ unsigned packf16(float a, float b) {
  f16x2 p; p.x = (__f16)a; p.y = (__f16)b;
  return __builtin_bit_cast(unsigned, p);
}

// ---------------- f16 MFMA GEMM: C[M,N] = A[M,K] @ W[N,K]^T (+bias +bias2) ----------------
template<bool ACC>
__global__ __launch_bounds__(256) void gemm_mfma(
    const float* __restrict__ A, const float* __restrict__ W, float* __restrict__ C,
    int M, int N, int K, int lda, int ldb, int ldc,
    const float* __restrict__ bias, const float* __restrict__ bias2)
{
  __shared__ uint4v As[1024];   // [row][8 kb-slots], phys slot = kb ^ (row&7), 16KB
  __shared__ uint4v Bs[1024];   // 16KB
  const int tid  = threadIdx.x;
  const int lane = tid & 63, wid = tid >> 6;
  const int wr = wid >> 1, wc = wid & 1;
  const int fr = lane & 15, fq = lane >> 4;
  const int m0 = blockIdx.y * 128, n0 = blockIdx.x * 128;
  const int srow = tid >> 3, skb = tid & 7;

  f32x4v acc[4][4] = {};
  for (int k0 = 0; k0 < K; k0 += 64) {
    const float* Abase = A + (size_t)m0 * lda + k0;
    const float* Bbase = W + (size_t)n0 * ldb + k0;
    #pragma unroll
    for (int i = 0; i < 4; ++i) {
      int row = srow + i * 32;
      const float4* pa = (const float4*)(Abase + (size_t)row * lda + skb * 8);
      const float4* pb = (const float4*)(Bbase + (size_t)row * ldb + skb * 8);
      float4 a0 = pa[0], a1 = pa[1];
      float4 b0 = pb[0], b1 = pb[1];
      uint4v ap, bp;
      ap.x = packf16(a0.x, a0.y); ap.y = packf16(a0.z, a0.w);
      ap.z = packf16(a1.x, a1.y); ap.w = packf16(a1.z, a1.w);
      bp.x = packf16(b0.x, b0.y); bp.y = packf16(b0.z, b0.w);
      bp.z = packf16(b1.x, b1.y); bp.w = packf16(b1.z, b1.w);
      As[row * 8 + (skb ^ (row & 7))] = ap;
      Bs[row * 8 + (skb ^ (row & 7))] = bp;
    }
    __syncthreads();
    #pragma unroll
    for (int ks = 0; ks < 2; ++ks) {
      half8 af[4], bf[4];
      #pragma unroll
      for (int mt = 0; mt < 4; ++mt) {
        int row = wr * 64 + mt * 16 + fr;
        int kb = ks * 4 + fq;
        af[mt] = __builtin_bit_cast(half8, As[row * 8 + (kb ^ (row & 7))]);
      }
      #pragma unroll
      for (int nt = 0; nt < 4; ++nt) {
        int row = wc * 64 + nt * 16 + fr;
        int kb = ks * 4 + fq;
        bf[nt] = __builtin_bit_cast(half8, Bs[row * 8 + (kb ^ (row & 7))]);
      }
      #pragma unroll
      for (int mt = 0; mt < 4; ++mt)
        #pragma unroll
        for (int nt = 0; nt < 4; ++nt)
          acc[mt][nt] = __builtin_amdgcn_mfma_f32_16x16x32_f16(af[mt], bf[nt], acc[mt][nt], 0, 0, 0);
    }
    __syncthreads();
  }
  #pragma unroll
  for (int nt = 0; nt < 4; ++nt) {
    int n = n0 + wc * 64 + nt * 16 + fr;
    float bv = (bias ? bias[n] : 0.f) + (bias2 ? bias2[n] : 0.f);
    #pragma unroll
    for (int mt = 0; mt < 4; ++mt) {
      #pragma unroll
      for (int r = 0; r < 4; ++r) {
        int m = m0 + wr * 64 + mt * 16 + fq * 4 + r;
        float v = acc[mt][nt][r] + bv;
        if (ACC) C[(size_t)m * ldc + n] += v; else C[(size_t)m * ldc + n] = v;
      }
    }
  }
}

// ---------------- fp32 fallback GEMM (small/odd shapes) ----------------
template<int ACT>
__global__ __launch_bounds__(256) void gemm_nt(
    const float* __restrict__ A, const float* __restrict__ Bm, float* __restrict__ C,
    int M, int N, int K, int lda, int ldb, int ldc,
    const float* __restrict__ bias)
{
  __shared__ __align__(16) float As[16][64];
  __shared__ __align__(16) float Bs[16][64];
  const int tid = threadIdx.x;
  const int tx = tid & 15, ty = tid >> 4;
  const int m0 = blockIdx.y * 64, n0 = blockIdx.x * 64;
  const int r = tid >> 2, kq = (tid & 3) * 4;
  float acc[4][4] = {};
  for (int k0 = 0; k0 < K; k0 += 16) {
    float4 av = *(const float4*)(A  + (size_t)(m0 + r) * lda + (k0 + kq));
    float4 bv = *(const float4*)(Bm + (size_t)(n0 + r) * ldb + (k0 + kq));
    As[kq+0][r] = av.x; As[kq+1][r] = av.y; As[kq+2][r] = av.z; As[kq+3][r] = av.w;
    Bs[kq+0][r] = bv.x; Bs[kq+1][r] = bv.y; Bs[kq+2][r] = bv.z; Bs[kq+3][r] = bv.w;
    __syncthreads();
    #pragma unroll
    for (int kk = 0; kk < 16; ++kk) {
      float4 a = *(const float4*)(&As[kk][ty*4]);
      float4 b = *(const float4*)(&Bs[kk][tx*4]);
      float aa[4] = {a.x, a.y, a.z, a.w};
      float bb[4] = {b.x, b.y, b.z, b.w};
      #pragma unroll
      for (int i = 0; i < 4; ++i)
        #pragma unroll
        for (int j = 0; j < 4; ++j)
          acc[i][j] = fmaf(aa[i], bb[j], acc[i][j]);
    }
    __syncthreads();
  }
  #pragma unroll
  for (int i = 0; i < 4; ++i) {
    int m = m0 + ty*4 + i;
    float* cp = C + (size_t)m * ldc + n0 + tx*4;
    #pragma unroll
    for (int j = 0; j < 4; ++j) {
      int n = n0 + tx*4 + j;
      float v = acc[i][j];
      if (bias)  v += bias[n];
      if (ACT == 1) v = (v > 20.f) ? v : log1pf(__expf(v));
      cp[j] = v;
    }
  }
}

// xpw_pad[r][k] = r<64 ? xpw[r][k] : 0   (128x1024)
__global__ __launch_bounds__(256) void pad_xpw(
    const float* __restrict__ src, float* __restrict__ dst)
{
  int t = blockIdx.x * 256 + threadIdx.x;
  int r = t >> 10;
  dst[t] = (r < 64) ? src[t] : 0.f;
}

// pack whh f32 -> f16 uint4, layout [dir][gate G][q][t] with t=(j<<1)|ks:
// wpk[((dir*4+G)*16+q)*512 + t] covers whh[dir][(G*256+j)][ks*128 + q*8 .. +8)
__global__ __launch_bounds__(256) void pack_whh(
    const float* __restrict__ whh, uint4* __restrict__ wpk)
{
  int idx = blockIdx.x * 256 + threadIdx.x;   // [0, 65536)
  int t = idx & 511;
  int q = (idx >> 9) & 15;
  int G = (idx >> 13) & 3;
  int dir = idx >> 15;
  int j = t >> 1, ks = t & 1;
  const float* src = whh + (size_t)dir * 262144 + (size_t)(G * 256 + j) * 256 + ks * 128 + q * 8;
  float4 fa = ((const float4*)src)[0];
  float4 fb = ((const float4*)src)[1];
  uint4 pk;
  pk.x = packf16(fa.x, fa.y); pk.y = packf16(fa.z, fa.w);
  pk.z = packf16(fb.x, fb.y); pk.w = packf16(fb.z, fb.w);
  wpk[idx] = pk;
}

// u[b,l,c] = silu(cb[c] + sum_k xin[b,l-3+k,c] * cw[c,k])
__global__ __launch_bounds__(256) void conv_silu(
    const float* __restrict__ xz, const float* __restrict__ cw, const float* __restrict__ cb,
    float* __restrict__ u)
{
  int t = blockIdx.x * 256 + threadIdx.x;
  int c  = t & (DIN - 1);
  int bl = t >> 10;
  int l  = bl & (L_ - 1);
  float acc = cb[c];
  #pragma unroll
  for (int k = 0; k < DCV; ++k) {
    int ls = l + k - (DCV - 1);
    if (ls >= 0)
      acc = fmaf(xz[(size_t)(bl + k - (DCV - 1)) * 2048 + c], cw[c * DCV + k], acc);
  }
  u[t] = acc * fast_sigmoid(acc);
}

// selective scan: thread per (b,c,n). 4-deep rotating software prefetch (named
// registers, statically unrolled x4) keeps ~20 loads in flight per thread --
// only 4 waves/CU are available (65536 threads fixed), so per-step latency must
// be hidden by ILP, not TLP. h-chain itself is ~15 cyc/step.
__global__ __launch_bounds__(256) void scan_kernel(
    const float* __restrict__ dt, const float* __restrict__ u,
    const float* __restrict__ xdbl, const float* __restrict__ xz,
    const float* __restrict__ A_log, const float* __restrict__ Dp,
    float* __restrict__ y)
{
  int t = blockIdx.x * 256 + threadIdx.x;
  int n  = t & 15;
  int bc = t >> 4;
  int c  = bc & (DIN - 1);
  int b  = bc >> 10;
  float Ac = -__expf(A_log[c * DST + n]);
  float Dc = Dp[c];
  float h = 0.f;
  const size_t row = (size_t)b * L_;

#define DECLP(i) float dtv##i, uv##i, Bn##i, Cn##i, zv##i;
  DECLP(0) DECLP(1) DECLP(2) DECLP(3)
#define LOADP(i, l) { \
    const size_t nb_ = row + (l); \
    dtv##i = dt[nb_ * DIN + c]; \
    uv##i  = u [nb_ * DIN + c]; \
    Bn##i  = xdbl[nb_ * 128 + 32 + n]; \
    Cn##i  = xdbl[nb_ * 128 + 48 + n]; \
    zv##i  = xz[nb_ * 2048 + 1024 + c]; }
#define STEPP(i, l) { \
    float dA_ = __expf(dtv##i * Ac); \
    h = fmaf(dA_, h, (dtv##i * uv##i) * Bn##i); \
    float p_ = h * Cn##i; \
    p_ += __shfl_xor(p_, 1, 64); \
    p_ += __shfl_xor(p_, 2, 64); \
    p_ += __shfl_xor(p_, 4, 64); \
    p_ += __shfl_xor(p_, 8, 64); \
    if (n == 0) { \
      float yv_ = p_ + uv##i * Dc; \
      yv_ *= zv##i * fast_sigmoid(zv##i); \
      y[(row + (l)) * DIN + c] = yv_; \
    } }

  LOADP(0, 0) LOADP(1, 1) LOADP(2, 2) LOADP(3, 3)
  for (int l = 0; l < L_ - 4; l += 4) {
    STEPP(0, l)     LOADP(0, l + 4)
    STEPP(1, l + 1) LOADP(1, l + 5)
    STEPP(2, l + 2) LOADP(2, l + 6)
    STEPP(3, l + 3) LOADP(3, l + 7)
  }
  STEPP(0, L_ - 4) STEPP(1, L_ - 3) STEPP(2, L_ - 2) STEPP(3, L_ - 1)
#undef DECLP
#undef LOADP
#undef STEPP
}

// out[row*ldo + c] = layernorm(a[row] + mo[row]) * g + b
__global__ __launch_bounds__(64) void resid_ln(
    const float* __restrict__ a, const float* __restrict__ mo,
    const float* __restrict__ g, const float* __restrict__ bta,
    float* __restrict__ outm, int ldo)
{
  int row = blockIdx.x;
  int lane = threadIdx.x;
  const float* pa = a  + (size_t)row * 512;
  const float* pb = mo + (size_t)row * 512;
  float v[8];
  float s = 0.f, s2 = 0.f;
  #pragma unroll
  for (int i = 0; i < 8; ++i) {
    float x = pa[lane + i * 64] + pb[lane + i * 64];
    v[i] = x; s += x; s2 += x * x;
  }
  #pragma unroll
  for (int off = 1; off < 64; off <<= 1) {
    s  += __shfl_xor(s,  off, 64);
    s2 += __shfl_xor(s2, off, 64);
  }
  float mean = s * (1.f / 512.f);
  float var  = s2 * (1.f / 512.f) - mean * mean;
  float rstd = rsqrtf(var + 1e-5f);
  #pragma unroll
  for (int i = 0; i < 8; ++i) {
    int cidx = lane + i * 64;
    outm[(size_t)row * ldo + cidx] = (v[i] - mean) * rstd * g[cidx] + bta[cidx];
  }
}

// ---------------- LSTM recurrence (r9 structure -- empirical best: 825us) ----------------
// Block per (dir,b), 512 threads = (unit j = t>>1) x (K-half ks = t&1).
// i,f,g gates as named uint4 from pre-packed f16 weights (compiler remats the
// loads in-loop -> 384 KB/step L2 stream, the measured per-CU L2 BW floor; all
// attempts to pin them in registers/AGPRs/in-loop-loads regressed, r10-r12).
// Gate o from LDS [q][t] (wave-contiguous). h packed-f16 in LDS, double-buffered.

#define WDECL(q) uint4 W0_##q, W1_##q, W2_##q;
#define LDG1(W, G, q) W = wp[((G) * 16 + (q)) * 512 + t];
#define WLOAD(q) LDG1(W0_##q, 0, q) LDG1(W1_##q, 1, q) LDG1(W2_##q, 2, q)
#define WSTEP(q) { \
    uint4 hv = h4s[buf][(q) * 2 + ks]; \
    uint4 wv = wo_lds[(q) * 512 + t]; \
    a0 = dot2f(W0_##q.x, hv.x, a0); a0 = dot2f(W0_##q.y, hv.y, a0); \
    a0 = dot2f(W0_##q.z, hv.z, a0); a0 = dot2f(W0_##q.w, hv.w, a0); \
    a1 = dot2f(W1_##q.x, hv.x, a1); a1 = dot2f(W1_##q.y, hv.y, a1); \
    a1 = dot2f(W1_##q.z, hv.z, a1); a1 = dot2f(W1_##q.w, hv.w, a1); \
    a2 = dot2f(W2_##q.x, hv.x, a2); a2 = dot2f(W2_##q.y, hv.y, a2); \
    a2 = dot2f(W2_##q.z, hv.z, a2); a2 = dot2f(W2_##q.w, hv.w, a2); \
    a3 = dot2f(wv.x, hv.x, a3); a3 = dot2f(wv.y, hv.y, a3); \
    a3 = dot2f(wv.z, hv.z, a3); a3 = dot2f(wv.w, hv.w, a3); }
#define REP16(M) M(0) M(1) M(2) M(3) M(4) M(5) M(6) M(7) \
                 M(8) M(9) M(10) M(11) M(12) M(13) M(14) M(15)

__global__ __launch_bounds__(512, 1) void lstm_rec(
    const float* __restrict__ gx, const uint4* __restrict__ wpk,
    float* __restrict__ comb)
{
  __shared__ uint4 wo_lds[16 * 512];            // [q][t], 128KB o-gate weights
  __shared__ __align__(16) uint4 h4s[2][32];    // [buf][q*2+ks], packed-f16 h
  const int dir = blockIdx.x >> 2, b = blockIdx.x & 3;
  const int t = threadIdx.x;
  const int j = t >> 1, ks = t & 1;
  const uint4* wp = wpk + (size_t)dir * 4 * 16 * 512;

  REP16(WDECL)
  REP16(WLOAD)

  #pragma unroll
  for (int q = 0; q < 16; ++q)
    wo_lds[q * 512 + t] = wp[(3 * 16 + q) * 512 + t];

  if (t < 256) ((unsigned*)h4s)[t] = 0u;
  float c_reg = 0.f;
  float* outp = comb + 512 + dir * 256;        // comb columns [512+dir*256, +256)
  const float* gxb = gx + (size_t)(b * L_) * 2048 + dir * 1024;
  const int offA = (ks ? 1 : 0) * 256 + j;   // ks0 -> gate i, ks1 -> gate f
  const int offB = (ks ? 3 : 2) * 256 + j;   // ks0 -> gate g, ks1 -> gate o
  const int p_   = t >> 2;
  const int hidx = ((p_ >> 2) & 15) * 8 + (p_ >> 6) * 4 + (p_ & 3);
  __syncthreads();

  int buf = 0;
  const int l0 = dir ? (L_ - 1) : 0;
  float pgA = gxb[(size_t)l0 * 2048 + offA];
  float pgB = gxb[(size_t)l0 * 2048 + offB];

  for (int s = 0; s < L_; ++s) {
    const int l = dir ? (L_ - 1 - s) : s;
    float pgA_n = 0.f, pgB_n = 0.f;
    if (s + 1 < L_) {
      const int ln = dir ? (L_ - 2 - s) : (s + 1);
      pgA_n = gxb[(size_t)ln * 2048 + offA];
      pgB_n = gxb[(size_t)ln * 2048 + offB];
    }
    float a0 = 0.f, a1 = 0.f, a2 = 0.f, a3 = 0.f;
    REP16(WSTEP)
    if (ks == 0) { a0 += pgA; a2 += pgB; } else { a1 += pgA; a3 += pgB; }
    a0 += __shfl_xor(a0, 1, 64);
    a1 += __shfl_xor(a1, 1, 64);
    a2 += __shfl_xor(a2, 1, 64);
    a3 += __shfl_xor(a3, 1, 64);
    const float si = fast_sigmoid(a0);
    const float sf = fast_sigmoid(a1);
    const float tg = fast_tanh(a2);
    const float so = fast_sigmoid(a3);
    c_reg = fmaf(sf, c_reg, si * tg);
    const float hv = so * fast_tanh(c_reg);
    if (ks == 0) outp[(size_t)(b * L_ + l) * 1024 + j] = hv;
    const float hv2 = __shfl_xor(hv, 2, 64);   // h of unit j+1 (for even j, ks=0)
    if ((t & 3) == 0)
      ((unsigned*)h4s[buf ^ 1])[hidx] = packf16(hv, hv2);
    pgA = pgA_n; pgB = pgB_n;
    buf ^= 1;
    __syncthreads();
  }
}

extern "C" void kernel_launch(void* const* d_in, const int* in_sizes, int n_in,
                              void* d_out, int out_size, void* d_ws, size_t ws_size,
                              hipStream_t stream)
{
  const float* x    = (const float*)d_in[0];
  const float* wi   = (const float*)d_in[1];
  const float* cw   = (const float*)d_in[2];
  const float* cb   = (const float*)d_in[3];
  const float* xpw  = (const float*)d_in[4];
  const float* dw   = (const float*)d_in[5];
  const float* db   = (const float*)d_in[6];
  const float* Alog = (const float*)d_in[7];
  const float* Dp   = (const float*)d_in[8];
  const float* wo   = (const float*)d_in[9];
  const float* lng  = (const float*)d_in[10];
  const float* lnb  = (const float*)d_in[11];
  const float* wih  = (const float*)d_in[12];
  const float* whh  = (const float*)d_in[13];
  const float* bih  = (const float*)d_in[14];
  const float* bhh  = (const float*)d_in[15];
  const float* fw   = (const float*)d_in[16];
  const float* fb   = (const float*)d_in[17];
  float* out = (float*)d_out;

  float* F    = (float*)d_ws;
  float* xz   = F;                 // 4,194,304 floats; aliased with gx
  float* gx   = F;
  float* u    = F + 4194304;       // 2,097,152
  float* xdbl = F + 6291456;       //   262,144 (2048 x 128, padded)
  float* dt   = F + 6553600;       // 2,097,152
  float* ybuf = F + 8650752;       // 2,097,152
  float* mo   = F + 10747904;      // 1,048,576
  float* mbuf = F + 11796480;      // 1,048,576
  float* comb = F + 12845056;      // 2,097,152  [m | lf | lb], ld 1024
  uint4* wpk  = (uint4*)(F + 14942208);  // 1MB packed whh
  float* xpw_pad = mo;             // pad consumed before mo is written

  const int M = B_ * L_;           // 2048
  dim3 blk(256);

  gemm_mfma<false><<<dim3(2048/128, M/128), blk, 0, stream>>>(
      x, wih, gx, M, 2048, 512, 512, 512, 2048, bih, bhh);
  pack_whh<<<dim3(256), blk, 0, stream>>>(whh, wpk);
  lstm_rec<<<dim3(8), dim3(512), 0, stream>>>(gx, wpk, comb);

  for (int i = 0; i < NL; ++i) {
    const float* min = (i == 0) ? x : mbuf;
    pad_xpw<<<dim3(512), blk, 0, stream>>>(xpw + (size_t)i*64*1024, xpw_pad);
    gemm_mfma<false><<<dim3(2048/128, M/128), blk, 0, stream>>>(
        min, wi + (size_t)i*2048*512, xz, M, 2048, 512, 512, 512, 2048, nullptr, nullptr);
    conv_silu<<<dim3((M*DIN)/256), blk, 0, stream>>>(
        xz, cw + (size_t)i*DIN*DCV, cb + i*DIN, u);
    gemm_mfma<false><<<dim3(1, M/128), blk, 0, stream>>>(
        u, xpw_pad, xdbl, M, 128, 1024, 1024, 1024, 128, nullptr, nullptr);
    gemm_nt<1><<<dim3(1024/64, M/64), blk, 0, stream>>>(
        xdbl, dw + (size_t)i*1024*32, dt, M, 1024, 32, 128, 32, 1024, db + i*1024);
    scan_kernel<<<dim3((B_*DIN*DST)/256), blk, 0, stream>>>(
        dt, u, xdbl, xz, Alog + (size_t)i*DIN*DST, Dp + i*DIN, ybuf);
    gemm_mfma<false><<<dim3(512/128, M/128), blk, 0, stream>>>(
        ybuf, wo + (size_t)i*512*1024, mo, M, 512, 1024, 1024, 1024, 512, nullptr, nullptr);
    if (i < NL - 1)
      resid_ln<<<dim3(M), dim3(64), 0, stream>>>(
          min, mo, lng + i*512, lnb + i*512, mbuf, 512);
    else
      resid_ln<<<dim3(M), dim3(64), 0, stream>>>(
          min, mo, lng + i*512, lnb + i*512, comb, 1024);
  }

  // fusion: out = comb @ fusion_w^T + fb  (single K=1024 MFMA GEMM)
  gemm_mfma<false><<<dim3(512/128, M/128), blk, 0, stream>>>(
      comb, fw, out, M, 512, 1024, 1024, 1024, 512, fb, nullptr);
}